// Round 17
// baseline (139.262 us; speedup 1.0000x reference)
//
#include <hip/hip_runtime.h>
#include <hip/hip_bf16.h>
#include <hip/hip_fp16.h>
#include <cstdint>
#include <cstddef>

typedef __bf16 bf16;
typedef __attribute__((ext_vector_type(8))) __bf16 bf16x8;
typedef __attribute__((ext_vector_type(16))) float f32x16;

static_assert(sizeof(bf16x8) == 16, "bf16x8 must be 16B");

#define NTASK 34
#define BTOT 16384
#define WSTRIDE 73728   // 36 ks-groups x 4 mt x 512 = 144KB/task = 9 windows x 16KB

__device__ __forceinline__ f32x16 mfma32(bf16x8 a, bf16x8 b, f32x16 c) {
  return __builtin_amdgcn_mfma_f32_32x32x16_bf16(a, b, c, 0, 0, 0);
}

__device__ __forceinline__ void gload_lds16(const void* g, void* l) {
  __builtin_amdgcn_global_load_lds((__attribute__((address_space(1))) void*)g,
                                   (__attribute__((address_space(3))) void*)l,
                                   16, 0, 0);
}

__device__ __forceinline__ unsigned pack2(float lo, float hi) {
  union { __bf16 h[2]; unsigned u; } v;
  v.h[0] = (__bf16)lo; v.h[1] = (__bf16)hi;
  return v.u;
}

__device__ __forceinline__ void pl32swap(unsigned &a, unsigned &b) {
  asm volatile("v_permlane32_swap_b32 %0, %1" : "+v"(a), "+v"(b));
}

// ---------------- prep (merged: weights + state frags + pprior) ----------------
// Weight stream per task: 36 ks-groups (4KB = 4 mt x 1KB A-frag), ks-major:
//   g in [0,16): W1 ks=g; g==16: b1 row; g==17: zero pad
//   g in [18,26): W2 ks=g-18; g==26: b2
//   g in [27,35): W3 ks=g-27; g==35: b3
__global__ void prep_all(const float* __restrict__ W1, const float* __restrict__ W2,
                         const float* __restrict__ W3, const float* __restrict__ b1,
                         const float* __restrict__ b2, const float* __restrict__ b3,
                         const float* __restrict__ state, const float* __restrict__ prior,
                         bf16* __restrict__ wdst, bf16* __restrict__ sdst,
                         float* __restrict__ ppt) {
  int bid = blockIdx.x;
  if (bid < 1224) {
    int idx = bid * 256 + threadIdx.x;    // 34*36*4*64 = 313344 exact
    int n = idx / 9216;
    int r = idx - n * 9216;
    int g = r >> 8;
    int m = (r >> 6) & 3;
    int l = r & 63;
    int col = m * 32 + (l & 31);
    int kj = (l >> 5) << 3;
    bf16x8 v;
#pragma unroll
    for (int j = 0; j < 8; ++j) v[j] = (bf16)0.f;
    if (g < 16) {
      const float* s = W1 + ((size_t)n * 256 + g * 16 + kj) * 128 + col;
#pragma unroll
      for (int j = 0; j < 8; ++j) v[j] = (bf16)s[(size_t)j * 128];
    } else if (g == 16) {
      if (l < 32) v[0] = (bf16)b1[n * 128 + col];
    } else if (g == 17) {
      // zero pad
    } else if (g < 26) {
      const float* s = W2 + ((size_t)n * 128 + (g - 18) * 16 + kj) * 128 + col;
#pragma unroll
      for (int j = 0; j < 8; ++j) v[j] = (bf16)s[(size_t)j * 128];
    } else if (g == 26) {
      if (l < 32) v[0] = (bf16)b2[n * 128 + col];
    } else if (g < 35) {
      const float* s = W3 + ((size_t)n * 128 + (g - 27) * 16 + kj) * 128 + col;
#pragma unroll
      for (int j = 0; j < 8; ++j) v[j] = (bf16)s[(size_t)j * 128];
    } else {
      if (l < 32) v[0] = (bf16)b3[n * 128 + col];
    }
    *(bf16x8*)(wdst + (size_t)n * WSTRIDE + (size_t)(g * 4 + m) * 512 + l * 8) = v;
  } else if (bid < 3272) {
    int idx = (bid - 1224) * 256 + threadIdx.x;   // 524288 exact
    int rb = idx >> 10;
    int r = idx & 1023;
    int ks = r >> 6;
    int l = r & 63;
    int b = rb * 32 + (l & 31);
    int k0 = ks * 16 + ((l >> 5) << 3);
    const float* s = state + (size_t)b * 256 + k0;
    bf16x8 v;
#pragma unroll
    for (int j = 0; j < 8; ++j) v[j] = (bf16)s[j];
    *(bf16x8*)(sdst + (size_t)(rb * 16 + ks) * 512 + l * 8) = v;
  } else {
    int row = (bid - 3272) * 4 + (threadIdx.x >> 6);
    int lane = threadIdx.x & 63;
    float v = (lane < NTASK) ? prior[(size_t)row * NTASK + lane] : -INFINITY;
    float m = v;
#pragma unroll
    for (int mm = 1; mm < 64; mm <<= 1) m = fmaxf(m, __shfl_xor(m, mm));
    float e = (lane < NTASK) ? expf(v - m) : 0.0f;
    float s = e;
#pragma unroll
    for (int mm = 1; mm < 64; mm <<= 1) s += __shfl_xor(s, mm);
    if (lane < NTASK) ppt[(size_t)lane * BTOT + row] = e / s;
  }
}

__global__ void prep_langn(const float* __restrict__ lang, float* __restrict__ out) {
  __shared__ float red[2];
  int n = blockIdx.x;
  int t = threadIdx.x;                        // 128 threads
  float v = lang[(size_t)n * 128 + t];
  float ss = v * v;
#pragma unroll
  for (int m = 1; m < 64; m <<= 1) ss += __shfl_xor(ss, m);
  if ((t & 63) == 0) red[t >> 6] = ss;
  __syncthreads();
  float s = red[0] + red[1];
  float sc = 1.0f / fmaxf(sqrtf(s), 1e-8f);
  out[(size_t)n * 128 + t] = v * sc;
}

// ---------------- pass 1: 3-slot window ring + XCD-pinned task groups ----------------
// grid = 512, 2 blocks/CU, one residency round. XCD swizzle: with round-robin
// dispatch XCD = bid&7; remap tg = (bid&7)>>1, rg = (bid>>3)*2 + (bid&1)
// (bijective) so each task group lives on exactly 2 XCDs -> its 1.3MB weight
// slice is L2-resident (vs 5MB random spread = L2 thrash -> L3 latency).
// Block = 4 waves x 32 rows, (256,2). State frags persistent in 16 regs.
// Depth-2 window prefetch, uniform counted wait vmcnt(4). Latent in f16 regs.

__global__ void __launch_bounds__(256, 2)
pass1_kernel(const int* __restrict__ task_id, const bf16* __restrict__ wstream,
             const bf16* __restrict__ sf, const float* __restrict__ langn,
             const float* __restrict__ pp_t,
             float* __restrict__ cs_t, __half* __restrict__ lat_part,
             float* __restrict__ out_tgt) {
  __shared__ __align__(16) bf16 shW[3 * 8192];   // 3 x 16KB window slots

  const int tid = threadIdx.x;
  const int l = tid & 63;
  const int wid = tid >> 6;        // wave 0..3
  const int hi = l >> 5;
  const int b = l & 31;
  const int bid = blockIdx.x;
  const int tg = (bid & 7) >> 1;              // task group 0..3 (XCD-pinned)
  const int rg = ((bid >> 3) << 1) | (bid & 1);  // row group 0..127
  const int start = (tg < 2) ? tg * 9 : (18 + (tg - 2) * 8);  // 0,9,18,26
  const int cnt = (tg < 2) ? 9 : 8;
  const int nwin = cnt * 9;
  const int row0 = rg * 128 + wid * 32 + b;
  const int rb0 = rg * 4 + wid;

  const int tidn = task_id[row0];
  const bf16* sb = sf + (size_t)rb0 * 8192 + l * 8;
  const bf16* wsrc = wstream + (size_t)start * WSTRIDE;

#define STAGE_WIN(slot, w) \
  { _Pragma("unroll") \
    for (int c = 0; c < 4; ++c) \
      gload_lds16(wsrc + (size_t)(w) * 8192 + c * 2048 + tid * 8, \
                  shW + (slot) * 8192 + c * 2048 + tid * 8); }

#define WIN_TOP() \
  { asm volatile("s_waitcnt vmcnt(4)" ::: "memory"); \
    __builtin_amdgcn_s_barrier(); }

#define KMFMA(slot, gi, bop) \
  { _Pragma("unroll") \
    for (int mt = 0; mt < 4; ++mt) { \
      bf16x8 wf = *(const bf16x8*)(shW + (slot) * 8192 + ((gi) * 4 + mt) * 512 + l * 8); \
      acc[mt] = mfma32(wf, (bop), acc[mt]); } }

  // prologue: stage windows 0,1; load ALL 16 state frags (persistent, task-invariant)
  STAGE_WIN(0, 0);
  STAGE_WIN(1, 1);
  bf16x8 sring[16];
#pragma unroll
  for (int i = 0; i < 16; ++i) sring[i] = *(const bf16x8*)(sb + i * 512);

  union { unsigned u[4]; bf16x8 v; } cf;   // const-1 B-frag (bias K-augment)
  cf.u[0] = (l < 32) ? 0x3f80u : 0u;
  cf.u[1] = 0u; cf.u[2] = 0u; cf.u[3] = 0u;

  f32x16 z;
#pragma unroll
  for (int i = 0; i < 16; ++i) z[i] = 0.f;

  const __half2 hz = __float2half2_rn(0.0f);
  __half2 lat[4][4][2];
#pragma unroll
  for (int mt = 0; mt < 4; ++mt)
#pragma unroll
    for (int q = 0; q < 4; ++q) { lat[mt][q][0] = hz; lat[mt][q][1] = hz; }

  auto transition = [&](f32x16* acc, bf16x8* f) {
#pragma unroll
    for (int mt = 0; mt < 4; ++mt) {
      unsigned p[8];
#pragma unroll
      for (int q = 0; q < 4; ++q) {
        p[2 * q]     = pack2(fmaxf(acc[mt][4 * q + 0], 0.f), fmaxf(acc[mt][4 * q + 1], 0.f));
        p[2 * q + 1] = pack2(fmaxf(acc[mt][4 * q + 2], 0.f), fmaxf(acc[mt][4 * q + 3], 0.f));
      }
      pl32swap(p[0], p[2]); pl32swap(p[1], p[3]);
      pl32swap(p[4], p[6]); pl32swap(p[5], p[7]);
      union { unsigned u[4]; bf16x8 v; } e, o;
      e.u[0] = p[0]; e.u[1] = p[1]; e.u[2] = p[2]; e.u[3] = p[3];
      o.u[0] = p[4]; o.u[1] = p[5]; o.u[2] = p[6]; o.u[3] = p[7];
      f[2 * mt] = e.v; f[2 * mt + 1] = o.v;
    }
  };

  for (int t = 0; t < cnt; ++t) {
    const int n = start + t;
    const int w0g = t * 9;           // global index of this task's window 0
    f32x16 acc[4];
    bf16x8 f2[8], f3[8];

    // ---- w9=0 (slot 0): G1 ks0-3
    WIN_TOP();
    if (w0g + 2 < nwin) STAGE_WIN(2, w0g + 2);
#pragma unroll
    for (int mt = 0; mt < 4; ++mt) acc[mt] = z;
    __builtin_amdgcn_s_setprio(1);
#pragma unroll
    for (int gi = 0; gi < 4; ++gi) KMFMA(0, gi, sring[gi]);
    __builtin_amdgcn_s_setprio(0);

    // ---- w9=1 (slot 1): G1 ks4-7
    WIN_TOP();
    if (w0g + 3 < nwin) STAGE_WIN(0, w0g + 3);
    __builtin_amdgcn_s_setprio(1);
#pragma unroll
    for (int gi = 0; gi < 4; ++gi) KMFMA(1, gi, sring[4 + gi]);
    __builtin_amdgcn_s_setprio(0);

    // ---- w9=2 (slot 2): G1 ks8-11
    WIN_TOP();
    if (w0g + 4 < nwin) STAGE_WIN(1, w0g + 4);
    __builtin_amdgcn_s_setprio(1);
#pragma unroll
    for (int gi = 0; gi < 4; ++gi) KMFMA(2, gi, sring[8 + gi]);
    __builtin_amdgcn_s_setprio(0);

    // ---- w9=3 (slot 0): G1 ks12-15
    WIN_TOP();
    if (w0g + 5 < nwin) STAGE_WIN(2, w0g + 5);
    __builtin_amdgcn_s_setprio(1);
#pragma unroll
    for (int gi = 0; gi < 4; ++gi) KMFMA(0, gi, sring[12 + gi]);
    __builtin_amdgcn_s_setprio(0);

    // ---- w9=4 (slot 1): b1 | pad | G2 ks0,1  (+ transition 1)
    WIN_TOP();
    if (w0g + 6 < nwin) STAGE_WIN(0, w0g + 6);
    __builtin_amdgcn_s_setprio(1);
    KMFMA(1, 0, cf.v);                 // b1 bias row
    __builtin_amdgcn_s_setprio(0);
    transition(acc, f2);
#pragma unroll
    for (int mt = 0; mt < 4; ++mt) acc[mt] = z;
    __builtin_amdgcn_s_setprio(1);
    KMFMA(1, 2, f2[0]);
    KMFMA(1, 3, f2[1]);
    __builtin_amdgcn_s_setprio(0);

    // ---- w9=5 (slot 2): G2 ks2-5
    WIN_TOP();
    if (w0g + 7 < nwin) STAGE_WIN(1, w0g + 7);
    __builtin_amdgcn_s_setprio(1);
#pragma unroll
    for (int gi = 0; gi < 4; ++gi) KMFMA(2, gi, f2[2 + gi]);
    __builtin_amdgcn_s_setprio(0);

    // ---- w9=6 (slot 0): G2 ks6,7 | b2 | G3 ks0  (+ transition 2)
    WIN_TOP();
    if (w0g + 8 < nwin) STAGE_WIN(2, w0g + 8);
    __builtin_amdgcn_s_setprio(1);
    KMFMA(0, 0, f2[6]);
    KMFMA(0, 1, f2[7]);
    KMFMA(0, 2, cf.v);                 // b2 bias row
    __builtin_amdgcn_s_setprio(0);
    transition(acc, f3);
#pragma unroll
    for (int mt = 0; mt < 4; ++mt) acc[mt] = z;
    __builtin_amdgcn_s_setprio(1);
    KMFMA(0, 3, f3[0]);
    __builtin_amdgcn_s_setprio(0);

    // ---- w9=7 (slot 1): G3 ks1-4
    WIN_TOP();
    if (w0g + 9 < nwin) STAGE_WIN(0, w0g + 9);
    __builtin_amdgcn_s_setprio(1);
#pragma unroll
    for (int gi = 0; gi < 4; ++gi) KMFMA(1, gi, f3[1 + gi]);
    __builtin_amdgcn_s_setprio(0);

    // ---- w9=8 (slot 2): G3 ks5-7 | b3; epilogue
    WIN_TOP();
    if (w0g + 10 < nwin) STAGE_WIN(1, w0g + 10);
    __builtin_amdgcn_s_setprio(1);
    KMFMA(2, 0, f3[5]);
    KMFMA(2, 1, f3[6]);
    KMFMA(2, 2, f3[7]);
    KMFMA(2, 3, cf.v);                 // b3 bias row
    __builtin_amdgcn_s_setprio(0);

    // ---- epilogue (stores only cause over-wait at next WIN_TOP; safe)
    float ssq = 0.f, dot = 0.f;
    const float* lgb = langn + (size_t)tidn * 128;
#pragma unroll
    for (int mt = 0; mt < 4; ++mt)
#pragma unroll
      for (int q = 0; q < 4; ++q) {
        int c0 = mt * 32 + q * 8 + 4 * hi;
        float4 lg = *(const float4*)(lgb + c0);
        float a0 = acc[mt][4 * q + 0], a1 = acc[mt][4 * q + 1];
        float a2 = acc[mt][4 * q + 2], a3 = acc[mt][4 * q + 3];
        ssq += a0 * a0 + a1 * a1 + a2 * a2 + a3 * a3;
        dot += a0 * lg.x + a1 * lg.y + a2 * lg.z + a3 * lg.w;
      }
    ssq += __shfl_xor(ssq, 32);
    dot += __shfl_xor(dot, 32);
    float inv = rsqrtf(ssq);
    if (l < 32) cs_t[(size_t)row0 * NTASK + n] = dot * inv;
    float pwi = pp_t[(size_t)n * BTOT + row0] * inv;
    __half2 pw2 = __float2half2_rn(pwi);
#pragma unroll
    for (int mt = 0; mt < 4; ++mt)
#pragma unroll
      for (int q = 0; q < 4; ++q) {
        lat[mt][q][0] = __hfma2(__floats2half2_rn(acc[mt][4 * q + 0], acc[mt][4 * q + 1]),
                                pw2, lat[mt][q][0]);
        lat[mt][q][1] = __hfma2(__floats2half2_rn(acc[mt][4 * q + 2], acc[mt][4 * q + 3]),
                                pw2, lat[mt][q][1]);
      }
    if (tidn == n) {
#pragma unroll
      for (int mt = 0; mt < 4; ++mt)
#pragma unroll
        for (int q = 0; q < 4; ++q) {
          float4 qv = {acc[mt][4 * q + 0] * inv, acc[mt][4 * q + 1] * inv,
                       acc[mt][4 * q + 2] * inv, acc[mt][4 * q + 3] * inv};
          *(float4*)(out_tgt + (size_t)row0 * 128 + mt * 32 + q * 8 + 4 * hi) = qv;
        }
    }
  }

  // ---- write f16 partial latent: lat_part[tg][row][128]
  __half* lp = lat_part + ((size_t)tg * BTOT + row0) * 128;
#pragma unroll
  for (int mt = 0; mt < 4; ++mt)
#pragma unroll
    for (int q = 0; q < 4; ++q) {
      int c0 = mt * 32 + q * 8 + 4 * hi;
      union { __half2 h[2]; uint2 u; } v;
      v.h[0] = lat[mt][q][0];
      v.h[1] = lat[mt][q][1];
      *(uint2*)(lp + c0) = v.u;
    }
#undef STAGE_WIN
#undef WIN_TOP
#undef KMFMA
}

// ---------------- pass 3: per-row combine (1 wave per row) ----------------

__global__ void __launch_bounds__(256)
pass3_kernel(const float* __restrict__ state, const float* __restrict__ cs_t,
             const __half* __restrict__ lat_part,
             float* __restrict__ out_rep, float* __restrict__ out_ltp,
             float* __restrict__ out_lat) {
  int w = threadIdx.x >> 6, l = threadIdx.x & 63;
  size_t row = (size_t)blockIdx.x * 4 + w;

  // log_softmax(cos*10)
  float c = (l < NTASK) ? cs_t[row * NTASK + l] * 10.0f : -1e30f;
  float cm = c;
#pragma unroll
  for (int mm = 1; mm < 64; mm <<= 1) cm = fmaxf(cm, __shfl_xor(cm, mm));
  float ce = (l < NTASK) ? expf(c - cm) : 0.0f;
  float cs = ce;
#pragma unroll
  for (int mm = 1; mm < 64; mm <<= 1) cs += __shfl_xor(cs, mm);
  if (l < NTASK) out_ltp[row * NTASK + l] = c - cm - logf(cs);

  // latent = sum of 4 f16 task-group partials
  float2 lv = {0.f, 0.f};
#pragma unroll
  for (int g = 0; g < 4; ++g) {
    __half2 p = *(const __half2*)(lat_part + ((size_t)g * BTOT + row) * 128 + 2 * l);
    lv.x += __low2float(p);
    lv.y += __high2float(p);
  }
  *(float2*)(out_lat + row * 128 + 2 * l) = lv;
  *(float2*)(out_rep + row * 384 + 256 + 2 * l) = lv;

  // state passthrough
  float4 sv = *(const float4*)(state + row * 256 + l * 4);
  *(float4*)(out_rep + row * 384 + l * 4) = sv;
}

// ---------------- launch ----------------

extern "C" void kernel_launch(void* const* d_in, const int* in_sizes, int n_in,
                              void* d_out, int out_size, void* d_ws, size_t ws_size,
                              hipStream_t stream) {
  (void)in_sizes; (void)n_in; (void)out_size; (void)ws_size;
  const float* state = (const float*)d_in[0];
  const int* task_id = (const int*)d_in[1];
  const float* prior = (const float*)d_in[2];
  const float* W1 = (const float*)d_in[3];
  const float* b1 = (const float*)d_in[4];
  const float* W2 = (const float*)d_in[5];
  const float* b2 = (const float*)d_in[6];
  const float* W3 = (const float*)d_in[7];
  const float* b3 = (const float*)d_in[8];
  const float* lang = (const float*)d_in[9];

  char* ws = (char*)d_ws;
  bf16* wstream  = (bf16*)(ws + 0);           //  5,013,504 B (34 x 144KB)
  bf16* sf       = (bf16*)(ws + 5013504);     //  8,388,608 B
  float* langn   = (float*)(ws + 13402112);   //     17,408 B
  float* pp_t    = (float*)(ws + 13419520);   //  2,228,224 B [34][16384]
  float* cs_t    = (float*)(ws + 15647744);   //  2,228,224 B [16384][34]
  __half* lat_part = (__half*)(ws + 17875968);// 16,777,216 B [4][16384][128] f16
                                              // total 34,653,184 B

  float* out = (float*)d_out;
  float* out_rep = out;                 // [B,384]
  float* out_ltp = out + 6291456;       // [B,34]
  float* out_tgt = out + 6848512;       // [B,128]
  float* out_lat = out + 8945664;       // [B,128]

  prep_all<<<7368, 256, 0, stream>>>(W1, W2, W3, b1, b2, b3, state, prior,
                                     wstream, sf, pp_t);
  prep_langn<<<NTASK, 128, 0, stream>>>(lang, langn);
  pass1_kernel<<<512, 256, 0, stream>>>(task_id, wstream, sf, langn, pp_t,
                                        cs_t, lat_part, out_tgt);
  pass3_kernel<<<4096, 256, 0, stream>>>(state, cs_t, lat_part,
                                         out_rep, out_ltp, out_lat);
}

// Round 18
// 133.497 us; speedup vs baseline: 1.0432x; 1.0432x over previous
//
#include <hip/hip_runtime.h>
#include <hip/hip_bf16.h>
#include <hip/hip_fp16.h>
#include <cstdint>
#include <cstddef>

typedef __bf16 bf16;
typedef __attribute__((ext_vector_type(8))) __bf16 bf16x8;
typedef __attribute__((ext_vector_type(16))) float f32x16;

static_assert(sizeof(bf16x8) == 16, "bf16x8 must be 16B");

#define NTASK 34
#define BTOT 16384
#define WSTRIDE 73728   // 36 ks-groups x 4 mt x 512 = 144KB/task = 6 windows x 24KB

__device__ __forceinline__ f32x16 mfma32(bf16x8 a, bf16x8 b, f32x16 c) {
  return __builtin_amdgcn_mfma_f32_32x32x16_bf16(a, b, c, 0, 0, 0);
}

__device__ __forceinline__ void gload_lds16(const void* g, void* l) {
  __builtin_amdgcn_global_load_lds((__attribute__((address_space(1))) void*)g,
                                   (__attribute__((address_space(3))) void*)l,
                                   16, 0, 0);
}

__device__ __forceinline__ unsigned pack2(float lo, float hi) {
  union { __bf16 h[2]; unsigned u; } v;
  v.h[0] = (__bf16)lo; v.h[1] = (__bf16)hi;
  return v.u;
}

__device__ __forceinline__ void pl32swap(unsigned &a, unsigned &b) {
  asm volatile("v_permlane32_swap_b32 %0, %1" : "+v"(a), "+v"(b));
}

// ---------------- prep (merged: weights + state frags + pprior) ----------------
// Weight stream per task: 36 ks-groups (4KB = 4 mt x 1KB A-frag), ks-major:
//   g in [0,16): W1 ks=g; g==16: b1 row; g==17: zero pad
//   g in [18,26): W2 ks=g-18; g==26: b2
//   g in [27,35): W3 ks=g-27; g==35: b3
__global__ void prep_all(const float* __restrict__ W1, const float* __restrict__ W2,
                         const float* __restrict__ W3, const float* __restrict__ b1,
                         const float* __restrict__ b2, const float* __restrict__ b3,
                         const float* __restrict__ state, const float* __restrict__ prior,
                         bf16* __restrict__ wdst, bf16* __restrict__ sdst,
                         float* __restrict__ ppt) {
  int bid = blockIdx.x;
  if (bid < 1224) {
    int idx = bid * 256 + threadIdx.x;    // 34*36*4*64 = 313344 exact
    int n = idx / 9216;
    int r = idx - n * 9216;
    int g = r >> 8;
    int m = (r >> 6) & 3;
    int l = r & 63;
    int col = m * 32 + (l & 31);
    int kj = (l >> 5) << 3;
    bf16x8 v;
#pragma unroll
    for (int j = 0; j < 8; ++j) v[j] = (bf16)0.f;
    if (g < 16) {
      const float* s = W1 + ((size_t)n * 256 + g * 16 + kj) * 128 + col;
#pragma unroll
      for (int j = 0; j < 8; ++j) v[j] = (bf16)s[(size_t)j * 128];
    } else if (g == 16) {
      if (l < 32) v[0] = (bf16)b1[n * 128 + col];
    } else if (g == 17) {
      // zero pad
    } else if (g < 26) {
      const float* s = W2 + ((size_t)n * 128 + (g - 18) * 16 + kj) * 128 + col;
#pragma unroll
      for (int j = 0; j < 8; ++j) v[j] = (bf16)s[(size_t)j * 128];
    } else if (g == 26) {
      if (l < 32) v[0] = (bf16)b2[n * 128 + col];
    } else if (g < 35) {
      const float* s = W3 + ((size_t)n * 128 + (g - 27) * 16 + kj) * 128 + col;
#pragma unroll
      for (int j = 0; j < 8; ++j) v[j] = (bf16)s[(size_t)j * 128];
    } else {
      if (l < 32) v[0] = (bf16)b3[n * 128 + col];
    }
    *(bf16x8*)(wdst + (size_t)n * WSTRIDE + (size_t)(g * 4 + m) * 512 + l * 8) = v;
  } else if (bid < 3272) {
    int idx = (bid - 1224) * 256 + threadIdx.x;   // 524288 exact
    int rb = idx >> 10;
    int r = idx & 1023;
    int ks = r >> 6;
    int l = r & 63;
    int b = rb * 32 + (l & 31);
    int k0 = ks * 16 + ((l >> 5) << 3);
    const float* s = state + (size_t)b * 256 + k0;
    bf16x8 v;
#pragma unroll
    for (int j = 0; j < 8; ++j) v[j] = (bf16)s[j];
    *(bf16x8*)(sdst + (size_t)(rb * 16 + ks) * 512 + l * 8) = v;
  } else {
    int row = (bid - 3272) * 4 + (threadIdx.x >> 6);
    int lane = threadIdx.x & 63;
    float v = (lane < NTASK) ? prior[(size_t)row * NTASK + lane] : -INFINITY;
    float m = v;
#pragma unroll
    for (int mm = 1; mm < 64; mm <<= 1) m = fmaxf(m, __shfl_xor(m, mm));
    float e = (lane < NTASK) ? expf(v - m) : 0.0f;
    float s = e;
#pragma unroll
    for (int mm = 1; mm < 64; mm <<= 1) s += __shfl_xor(s, mm);
    if (lane < NTASK) ppt[(size_t)lane * BTOT + row] = e / s;
  }
}

__global__ void prep_langn(const float* __restrict__ lang, float* __restrict__ out) {
  __shared__ float red[2];
  int n = blockIdx.x;
  int t = threadIdx.x;                        // 128 threads
  float v = lang[(size_t)n * 128 + t];
  float ss = v * v;
#pragma unroll
  for (int m = 1; m < 64; m <<= 1) ss += __shfl_xor(ss, m);
  if ((t & 63) == 0) red[t >> 6] = ss;
  __syncthreads();
  float s = red[0] + red[1];
  float sc = 1.0f / fmaxf(sqrtf(s), 1e-8f);
  out[(size_t)n * 128 + t] = v * sc;
}

// ---------------- pass 1: 3-slot 24KB window ring (6 barriers/task) ----------------
// grid = 512: bid = tg*128 + rg (r16 mapping) -> 2 blocks/CU, one residency round.
// Block = 4 waves x 32 rows, (256,2). LDS = 3 x 24KB slots = 72KB.
// State frags persistent in 16 regs; latent f32 in 64 regs (r16-proven budget).
// Depth-2 window prefetch; counted wait vmcnt(6) (= stage(w+1) in flight).

__global__ void __launch_bounds__(256, 2)
pass1_kernel(const int* __restrict__ task_id, const bf16* __restrict__ wstream,
             const bf16* __restrict__ sf, const float* __restrict__ langn,
             const float* __restrict__ pp_t,
             float* __restrict__ cs_t, __half* __restrict__ lat_part,
             float* __restrict__ out_tgt) {
  __shared__ __align__(16) bf16 shW[3 * 12288];   // 3 x 24KB window slots

  const int tid = threadIdx.x;
  const int l = tid & 63;
  const int wid = tid >> 6;        // wave 0..3
  const int hi = l >> 5;
  const int b = l & 31;
  const int tg = blockIdx.x >> 7;  // task group 0..3
  const int rg = blockIdx.x & 127; // 128-row group
  const int start = (tg < 2) ? tg * 9 : (18 + (tg - 2) * 8);  // 0,9,18,26
  const int cnt = (tg < 2) ? 9 : 8;
  const int nwin = cnt * 6;
  const int row0 = rg * 128 + wid * 32 + b;
  const int rb0 = rg * 4 + wid;

  const int tidn = task_id[row0];
  const bf16* sb = sf + (size_t)rb0 * 8192 + l * 8;
  const bf16* wsrc = wstream + (size_t)start * WSTRIDE;

#define STAGE_WIN(slot, w) \
  { _Pragma("unroll") \
    for (int c = 0; c < 6; ++c) \
      gload_lds16(wsrc + (size_t)(w) * 12288 + c * 2048 + tid * 8, \
                  shW + (slot) * 12288 + c * 2048 + tid * 8); }

#define WIN_TOP() \
  { asm volatile("s_waitcnt vmcnt(6)" ::: "memory"); \
    __builtin_amdgcn_s_barrier(); }

#define KMFMA(slot, gi, bop) \
  { _Pragma("unroll") \
    for (int mt = 0; mt < 4; ++mt) { \
      bf16x8 wf = *(const bf16x8*)(shW + (slot) * 12288 + ((gi) * 4 + mt) * 512 + l * 8); \
      acc[mt] = mfma32(wf, (bop), acc[mt]); } }

  // prologue: stage windows 0,1; load ALL 16 state frags (persistent, task-invariant)
  STAGE_WIN(0, 0);
  STAGE_WIN(1, 1);
  bf16x8 sring[16];
#pragma unroll
  for (int i = 0; i < 16; ++i) sring[i] = *(const bf16x8*)(sb + i * 512);

  union { unsigned u[4]; bf16x8 v; } cf;   // const-1 B-frag (bias K-augment)
  cf.u[0] = (l < 32) ? 0x3f80u : 0u;
  cf.u[1] = 0u; cf.u[2] = 0u; cf.u[3] = 0u;

  f32x16 z;
#pragma unroll
  for (int i = 0; i < 16; ++i) z[i] = 0.f;
  f32x16 lat[4] = {z, z, z, z};

  auto transition = [&](f32x16* acc, bf16x8* f) {
#pragma unroll
    for (int mt = 0; mt < 4; ++mt) {
      unsigned p[8];
#pragma unroll
      for (int q = 0; q < 4; ++q) {
        p[2 * q]     = pack2(fmaxf(acc[mt][4 * q + 0], 0.f), fmaxf(acc[mt][4 * q + 1], 0.f));
        p[2 * q + 1] = pack2(fmaxf(acc[mt][4 * q + 2], 0.f), fmaxf(acc[mt][4 * q + 3], 0.f));
      }
      pl32swap(p[0], p[2]); pl32swap(p[1], p[3]);
      pl32swap(p[4], p[6]); pl32swap(p[5], p[7]);
      union { unsigned u[4]; bf16x8 v; } e, o;
      e.u[0] = p[0]; e.u[1] = p[1]; e.u[2] = p[2]; e.u[3] = p[3];
      o.u[0] = p[4]; o.u[1] = p[5]; o.u[2] = p[6]; o.u[3] = p[7];
      f[2 * mt] = e.v; f[2 * mt + 1] = o.v;
    }
  };

  for (int t = 0; t < cnt; ++t) {
    const int n = start + t;
    const int w0g = t * 6;           // global index of this task's window 0
    f32x16 acc[4];
    bf16x8 f2[8], f3[8];

    // ---- w0 (slot w0g%3): G1 ks0-5
    WIN_TOP();
    if (w0g + 2 < nwin) STAGE_WIN((w0g + 2) % 3, w0g + 2);
#pragma unroll
    for (int mt = 0; mt < 4; ++mt) acc[mt] = z;
    __builtin_amdgcn_s_setprio(1);
#pragma unroll
    for (int gi = 0; gi < 6; ++gi) KMFMA((w0g) % 3, gi, sring[gi]);
    __builtin_amdgcn_s_setprio(0);

    // ---- w1: G1 ks6-11
    WIN_TOP();
    if (w0g + 3 < nwin) STAGE_WIN((w0g + 3) % 3, w0g + 3);
    __builtin_amdgcn_s_setprio(1);
#pragma unroll
    for (int gi = 0; gi < 6; ++gi) KMFMA((w0g + 1) % 3, gi, sring[6 + gi]);
    __builtin_amdgcn_s_setprio(0);

    // ---- w2: G1 ks12-15 + b1 + pad(skip); transition 1
    WIN_TOP();
    if (w0g + 4 < nwin) STAGE_WIN((w0g + 4) % 3, w0g + 4);
    __builtin_amdgcn_s_setprio(1);
#pragma unroll
    for (int gi = 0; gi < 4; ++gi) KMFMA((w0g + 2) % 3, gi, sring[12 + gi]);
    KMFMA((w0g + 2) % 3, 4, cf.v);       // b1 bias row
    __builtin_amdgcn_s_setprio(0);
    transition(acc, f2);

    // ---- w3: G2 ks0-5
    WIN_TOP();
    if (w0g + 5 < nwin) STAGE_WIN((w0g + 5) % 3, w0g + 5);
#pragma unroll
    for (int mt = 0; mt < 4; ++mt) acc[mt] = z;
    __builtin_amdgcn_s_setprio(1);
#pragma unroll
    for (int gi = 0; gi < 6; ++gi) KMFMA((w0g + 3) % 3, gi, f2[gi]);
    __builtin_amdgcn_s_setprio(0);

    // ---- w4: G2 ks6,7 + b2 | transition 2 | G3 ks0-2
    WIN_TOP();
    if (w0g + 6 < nwin) STAGE_WIN((w0g + 6) % 3, w0g + 6);
    __builtin_amdgcn_s_setprio(1);
    KMFMA((w0g + 4) % 3, 0, f2[6]);
    KMFMA((w0g + 4) % 3, 1, f2[7]);
    KMFMA((w0g + 4) % 3, 2, cf.v);       // b2 bias row
    __builtin_amdgcn_s_setprio(0);
    transition(acc, f3);
#pragma unroll
    for (int mt = 0; mt < 4; ++mt) acc[mt] = z;
    __builtin_amdgcn_s_setprio(1);
    KMFMA((w0g + 4) % 3, 3, f3[0]);
    KMFMA((w0g + 4) % 3, 4, f3[1]);
    KMFMA((w0g + 4) % 3, 5, f3[2]);
    __builtin_amdgcn_s_setprio(0);

    // ---- w5: G3 ks3-7 + b3; epilogue
    WIN_TOP();
    if (w0g + 7 < nwin) STAGE_WIN((w0g + 7) % 3, w0g + 7);
    __builtin_amdgcn_s_setprio(1);
#pragma unroll
    for (int gi = 0; gi < 5; ++gi) KMFMA((w0g + 5) % 3, gi, f3[3 + gi]);
    KMFMA((w0g + 5) % 3, 5, cf.v);       // b3 bias row
    __builtin_amdgcn_s_setprio(0);

    // ---- epilogue (stores only cause over-wait at next WIN_TOP; safe)
    float ssq = 0.f, dot = 0.f;
    const float* lgb = langn + (size_t)tidn * 128;
#pragma unroll
    for (int mt = 0; mt < 4; ++mt)
#pragma unroll
      for (int q = 0; q < 4; ++q) {
        int c0 = mt * 32 + q * 8 + 4 * hi;
        float4 lg = *(const float4*)(lgb + c0);
        float a0 = acc[mt][4 * q + 0], a1 = acc[mt][4 * q + 1];
        float a2 = acc[mt][4 * q + 2], a3 = acc[mt][4 * q + 3];
        ssq += a0 * a0 + a1 * a1 + a2 * a2 + a3 * a3;
        dot += a0 * lg.x + a1 * lg.y + a2 * lg.z + a3 * lg.w;
      }
    ssq += __shfl_xor(ssq, 32);
    dot += __shfl_xor(dot, 32);
    float inv = rsqrtf(ssq);
    if (l < 32) cs_t[(size_t)row0 * NTASK + n] = dot * inv;
    float pwi = pp_t[(size_t)n * BTOT + row0] * inv;
#pragma unroll
    for (int mt = 0; mt < 4; ++mt) lat[mt] += acc[mt] * pwi;
    if (tidn == n) {
#pragma unroll
      for (int mt = 0; mt < 4; ++mt)
#pragma unroll
        for (int q = 0; q < 4; ++q) {
          float4 qv = {acc[mt][4 * q + 0] * inv, acc[mt][4 * q + 1] * inv,
                       acc[mt][4 * q + 2] * inv, acc[mt][4 * q + 3] * inv};
          *(float4*)(out_tgt + (size_t)row0 * 128 + mt * 32 + q * 8 + 4 * hi) = qv;
        }
    }
  }

  // ---- write f16 partial latent: lat_part[tg][row][128]
  __half* lp = lat_part + ((size_t)tg * BTOT + row0) * 128;
#pragma unroll
  for (int mt = 0; mt < 4; ++mt)
#pragma unroll
    for (int q = 0; q < 4; ++q) {
      int c0 = mt * 32 + q * 8 + 4 * hi;
      union { __half h[4]; uint2 u; } v;
      v.h[0] = __float2half(lat[mt][4 * q + 0]);
      v.h[1] = __float2half(lat[mt][4 * q + 1]);
      v.h[2] = __float2half(lat[mt][4 * q + 2]);
      v.h[3] = __float2half(lat[mt][4 * q + 3]);
      *(uint2*)(lp + c0) = v.u;
    }
#undef STAGE_WIN
#undef WIN_TOP
#undef KMFMA
}

// ---------------- pass 3: per-row combine (1 wave per row) ----------------

__global__ void __launch_bounds__(256)
pass3_kernel(const float* __restrict__ state, const float* __restrict__ cs_t,
             const __half* __restrict__ lat_part,
             float* __restrict__ out_rep, float* __restrict__ out_ltp,
             float* __restrict__ out_lat) {
  int w = threadIdx.x >> 6, l = threadIdx.x & 63;
  size_t row = (size_t)blockIdx.x * 4 + w;

  // log_softmax(cos*10)
  float c = (l < NTASK) ? cs_t[row * NTASK + l] * 10.0f : -1e30f;
  float cm = c;
#pragma unroll
  for (int mm = 1; mm < 64; mm <<= 1) cm = fmaxf(cm, __shfl_xor(cm, mm));
  float ce = (l < NTASK) ? expf(c - cm) : 0.0f;
  float cs = ce;
#pragma unroll
  for (int mm = 1; mm < 64; mm <<= 1) cs += __shfl_xor(cs, mm);
  if (l < NTASK) out_ltp[row * NTASK + l] = c - cm - logf(cs);

  // latent = sum of 4 f16 task-group partials
  float2 lv = {0.f, 0.f};
#pragma unroll
  for (int g = 0; g < 4; ++g) {
    __half2 p = *(const __half2*)(lat_part + ((size_t)g * BTOT + row) * 128 + 2 * l);
    lv.x += __low2float(p);
    lv.y += __high2float(p);
  }
  *(float2*)(out_lat + row * 128 + 2 * l) = lv;
  *(float2*)(out_rep + row * 384 + 256 + 2 * l) = lv;

  // state passthrough
  float4 sv = *(const float4*)(state + row * 256 + l * 4);
  *(float4*)(out_rep + row * 384 + l * 4) = sv;
}

// ---------------- launch ----------------

extern "C" void kernel_launch(void* const* d_in, const int* in_sizes, int n_in,
                              void* d_out, int out_size, void* d_ws, size_t ws_size,
                              hipStream_t stream) {
  (void)in_sizes; (void)n_in; (void)out_size; (void)ws_size;
  const float* state = (const float*)d_in[0];
  const int* task_id = (const int*)d_in[1];
  const float* prior = (const float*)d_in[2];
  const float* W1 = (const float*)d_in[3];
  const float* b1 = (const float*)d_in[4];
  const float* W2 = (const float*)d_in[5];
  const float* b2 = (const float*)d_in[6];
  const float* W3 = (const float*)d_in[7];
  const float* b3 = (const float*)d_in[8];
  const float* lang = (const float*)d_in[9];

  char* ws = (char*)d_ws;
  bf16* wstream  = (bf16*)(ws + 0);           //  5,013,504 B (34 x 144KB)
  bf16* sf       = (bf16*)(ws + 5013504);     //  8,388,608 B
  float* langn   = (float*)(ws + 13402112);   //     17,408 B
  float* pp_t    = (float*)(ws + 13419520);   //  2,228,224 B [34][16384]
  float* cs_t    = (float*)(ws + 15647744);   //  2,228,224 B [16384][34]
  __half* lat_part = (__half*)(ws + 17875968);// 16,777,216 B [4][16384][128] f16
                                              // total 34,653,184 B

  float* out = (float*)d_out;
  float* out_rep = out;                 // [B,384]
  float* out_ltp = out + 6291456;       // [B,34]
  float* out_tgt = out + 6848512;       // [B,128]
  float* out_lat = out + 8945664;       // [B,128]

  prep_all<<<7368, 256, 0, stream>>>(W1, W2, W3, b1, b2, b3, state, prior,
                                     wstream, sf, pp_t);
  prep_langn<<<NTASK, 128, 0, stream>>>(lang, langn);
  pass1_kernel<<<512, 256, 0, stream>>>(task_id, wstream, sf, langn, pp_t,
                                        cs_t, lat_part, out_tgt);
  pass3_kernel<<<4096, 256, 0, stream>>>(state, cs_t, lat_part,
                                         out_rep, out_ltp, out_lat);
}